// Round 1
// baseline (239.204 us; speedup 1.0000x reference)
//
#include <hip/hip_runtime.h>

// Problem constants (from reference)
#define HD 64
#define VOCAB 64
#define SEQ 48
#define TSTRIDE 66   // table row stride in floats (64 data + 2 pad): float2-aligned, 16 bank-rotation classes

using frag_ab = __attribute__((ext_vector_type(8))) short;   // 8 bf16
using frag_cd = __attribute__((ext_vector_type(4))) float;   // 4 fp32
typedef __attribute__((ext_vector_type(4))) float floatx4;

static __device__ inline unsigned short f2bf(float f) {
  // round-to-nearest-even fp32 -> bf16
  unsigned u = __float_as_uint(f);
  unsigned r = (u + 0x7fffu + ((u >> 16) & 1u)) >> 16;
  return (unsigned short)r;
}

// Kernel A: build fused first-layer tables in workspace.
// T1[v][j] = sum_k embed[v][k]*W1[j][k] + b1[j]          (query half)
// T2[v][j] = 0.25 * sum_k embed[v][k]*W1[j][64+k]        (memory half, mean folded)
__global__ void build_tables(const float* __restrict__ embed,
                             const float* __restrict__ W1,
                             const float* __restrict__ b1,
                             float* __restrict__ T) {
  int v = blockIdx.x;    // 0..63
  int j = threadIdx.x;   // 0..63
  const float* e = embed + v * HD;
  const float* w1r = W1 + j * (2 * HD);
  float s1 = 0.f, s2 = 0.f;
  for (int k = 0; k < HD; ++k) {
    float ev = e[k];              // uniform per block -> scalar loads
    s1 += ev * w1r[k];
    s2 += ev * w1r[HD + k];
  }
  T[v * TSTRIDE + j] = s1 + b1[j];
  T[VOCAB * TSTRIDE + v * TSTRIDE + j] = 0.25f * s2;
}

// Kernel B v2: latency-pipelined.
// Each wave owns "groups" of 4 batches (= 64 output rows). Lane i holds the 5
// tokens of row g*64+i (loaded with ONE coalesced qtok dword + dword/dwordx4
// from seqs). Iterations then get their tokens via __shfl — no per-iteration
// global-load wait. Next group's tokens are prefetched before computing the
// current group (software pipeline). Grid = 1024 blocks = exactly 4/CU
// resident (one LDS-staging round).
__global__ __launch_bounds__(256, 4) void lru_main(
    const int* __restrict__ seqs, const int* __restrict__ qtok,
    const float* __restrict__ W2, const float* __restrict__ b2,
    const float* __restrict__ T, float* __restrict__ out, int nbatch) {
  __shared__ __align__(16) float sT[2 * VOCAB * TSTRIDE];   // 33792 B: T1 then T2

  const int lane = threadIdx.x & 63;
  const int quad = lane >> 4;
  const int m    = lane & 15;
  const int k0   = quad * 8;

  const int wave = blockIdx.x * (blockDim.x >> 6) + (threadIdx.x >> 6);
  const int nw   = gridDim.x * (blockDim.x >> 6);
  const int R    = nbatch * 16;             // total rows
  const int ngroup = (nbatch + 3) >> 2;     // groups of 4 batches (64 rows)

  // ---- issue first group's token loads NOW; they complete under staging ----
  int g = wave;
  int q_cur = 0, a_cur = 0;
  int4 b_cur = make_int4(0, 0, 0, 0);
  if (g < ngroup) {
    int r = g * 64 + lane; if (r >= R) r = R - 1;
    q_cur = qtok[r];                          // 256B fully coalesced per wave
    const int* sp = seqs + (size_t)r * SEQ;
    a_cur = sp[43];                           // col 43
    b_cur = *(const int4*)(sp + 44);          // cols 44,45,46,(47 unused); 16B-aligned
  }

  // cooperative stage of both tables (contiguous in ws)
  {
    const floatx4* src = (const floatx4*)T;
    floatx4* dst = (floatx4*)sT;
    const int n4 = 2 * VOCAB * TSTRIDE / 4;   // 2112
    for (int i = threadIdx.x; i < n4; i += blockDim.x) dst[i] = src[i];
  }
  __syncthreads();

  // B fragments: B[k][n] with n = lane&15 (+16*t), k = s*32 + quad*8 + j.
  frag_ab bf[4][2];
  for (int t = 0; t < 4; ++t)
    for (int s = 0; s < 2; ++s) {
      const float* w2r = W2 + (t * 16 + m) * HD + s * 32 + k0;
      for (int j = 0; j < 8; ++j) bf[t][s][j] = (short)f2bf(w2r[j]);
    }
  float b2v[4];
  for (int t = 0; t < 4; ++t) b2v[t] = b2[t * 16 + m];

  const float* T1 = sT;
  const float* T2 = sT + VOCAB * TSTRIDE;

  for (; g < ngroup; g += nw) {
    // ---- prefetch NEXT group's tokens (overlaps with this group's compute) ----
    const int gn = g + nw;
    int q_nxt = 0, a_nxt = 0;
    int4 b_nxt = make_int4(0, 0, 0, 0);
    if (gn < ngroup) {
      int r = gn * 64 + lane; if (r >= R) r = R - 1;
      q_nxt = qtok[r];
      const int* sp = seqs + (size_t)r * SEQ;
      a_nxt = sp[43];
      b_nxt = *(const int4*)(sp + 44);
    }

#pragma unroll
    for (int it = 0; it < 4; ++it) {
      const int b = g * 4 + it;
      if (b >= nbatch) break;                 // wave-uniform guard

      // tokens for row it*16+m live in lane it*16+m
      const int src = it * 16 + m;
      const int q  = __shfl(q_cur, src);
      const int t0 = __shfl(a_cur, src);
      const int t1 = __shfl(b_cur.x, src);
      const int t2 = __shfl(b_cur.y, src);
      const int t3 = __shfl(b_cur.z, src);

      // gather + sum 5 table rows at my 16 k-slots: k = k0+0..7 and 32+k0+0..7
      float2 a[8];
      {
        const float2* p1  = (const float2*)(T1 + q * TSTRIDE + k0);
        const float2* p1b = (const float2*)(T1 + q * TSTRIDE + 32 + k0);
        for (int c = 0; c < 4; ++c) { a[c] = p1[c]; a[4 + c] = p1b[c]; }
        const int toks[4] = {t0, t1, t2, t3};
        for (int u = 0; u < 4; ++u) {
          const float2* p2  = (const float2*)(T2 + toks[u] * TSTRIDE + k0);
          const float2* p2b = (const float2*)(T2 + toks[u] * TSTRIDE + 32 + k0);
          for (int c = 0; c < 4; ++c) {
            float2 x = p2[c], y = p2b[c];
            a[c].x += x.x; a[c].y += x.y;
            a[4 + c].x += y.x; a[4 + c].y += y.y;
          }
        }
      }

      // relu + bf16 pack into A fragments: A[m=lane&15][k=quad*8+j] (+32 for a1)
      frag_ab a0, a1;
      for (int c = 0; c < 4; ++c) {
        a0[2 * c]     = (short)f2bf(fmaxf(a[c].x, 0.f));
        a0[2 * c + 1] = (short)f2bf(fmaxf(a[c].y, 0.f));
        a1[2 * c]     = (short)f2bf(fmaxf(a[4 + c].x, 0.f));
        a1[2 * c + 1] = (short)f2bf(fmaxf(a[4 + c].y, 0.f));
      }

      frag_cd acc[4];
      for (int t = 0; t < 4; ++t) {
        acc[t] = (frag_cd){0.f, 0.f, 0.f, 0.f};
        acc[t] = __builtin_amdgcn_mfma_f32_16x16x32_bf16(a0, bf[t][0], acc[t], 0, 0, 0);
        acc[t] = __builtin_amdgcn_mfma_f32_16x16x32_bf16(a1, bf[t][1], acc[t], 0, 0, 0);
      }

      // C layout: col = lane&15, row = quad*4 + reg. Nontemporal: write-once stream.
      float* orow = out + (size_t)(b * 16) * HD;
      for (int t = 0; t < 4; ++t)
        for (int p = 0; p < 4; ++p)
          __builtin_nontemporal_store(acc[t][p] + b2v[t],
                                      &orow[(quad * 4 + p) * HD + t * 16 + m]);
    }

    q_cur = q_nxt; a_cur = a_nxt; b_cur = b_nxt;
  }
}

extern "C" void kernel_launch(void* const* d_in, const int* in_sizes, int n_in,
                              void* d_out, int out_size, void* d_ws, size_t ws_size,
                              hipStream_t stream) {
  const int*   seqs  = (const int*)d_in[0];
  const int*   qtok  = (const int*)d_in[1];
  const float* embed = (const float*)d_in[2];
  const float* W1    = (const float*)d_in[3];
  const float* b1    = (const float*)d_in[4];
  const float* W2    = (const float*)d_in[5];
  const float* b2    = (const float*)d_in[6];
  float* out = (float*)d_out;
  float* T   = (float*)d_ws;   // 2*64*66 floats = 33792 B

  const int B = in_sizes[1];        // number of rows (524288)
  const int nbatch = B / 16;

  build_tables<<<VOCAB, HD, 0, stream>>>(embed, W1, b1, T);
  lru_main<<<1024, 256, 0, stream>>>(seqs, qtok, W2, b2, T, out, nbatch);
}

// Round 2
// 239.019 us; speedup vs baseline: 1.0008x; 1.0008x over previous
//
#include <hip/hip_runtime.h>

// Problem constants (from reference)
#define HD 64
#define VOCAB 64
#define SEQ 48

// Tables are bf16, row = 64 bf16 = 128 B = 8 chunks of 16 B.
// Chunk c of row r is stored at chunk position (c ^ (r & 7)) — XOR swizzle so a
// wave's 64 b128 reads (random rows) spread uniformly over all 8 bank groups.
// Same-row same-chunk lanes hit the same address -> LDS broadcast (free).
#define TROWS 128            // 64 T1 rows then 64 T2 rows
#define TELEMS (TROWS * 64)  // ushort count = 8192 -> 16384 B

using frag_ab = __attribute__((ext_vector_type(8))) short;   // 8 bf16
using frag_cd = __attribute__((ext_vector_type(4))) float;   // 4 fp32
typedef __attribute__((ext_vector_type(4))) float floatx4;
typedef __attribute__((ext_vector_type(4))) unsigned int uintx4;

static __device__ inline unsigned short f2bf(float f) {
  // round-to-nearest-even fp32 -> bf16
  unsigned u = __float_as_uint(f);
  unsigned r = (u + 0x7fffu + ((u >> 16) & 1u)) >> 16;
  return (unsigned short)r;
}
static __device__ inline float blo(unsigned w) { return __uint_as_float(w << 16); }
static __device__ inline float bhi(unsigned w) { return __uint_as_float(w & 0xffff0000u); }

// Kernel A: build fused first-layer tables in workspace (bf16, chunk-swizzled).
// T1[v][j] = sum_k embed[v][k]*W1[j][k] + b1[j]          (query half)
// T2[v][j] = 0.25 * sum_k embed[v][k]*W1[j][64+k]        (memory half, mean folded)
__global__ void build_tables(const float* __restrict__ embed,
                             const float* __restrict__ W1,
                             const float* __restrict__ b1,
                             unsigned short* __restrict__ T) {
  int v = blockIdx.x;    // 0..63
  int j = threadIdx.x;   // 0..63
  const float* e = embed + v * HD;
  const float* w1r = W1 + j * (2 * HD);
  float s1 = 0.f, s2 = 0.f;
  for (int k = 0; k < HD; ++k) {
    float ev = e[k];              // uniform per block -> scalar loads
    s1 += ev * w1r[k];
    s2 += ev * w1r[HD + k];
  }
  // swizzled element position within a row: chunk (j>>3) -> (j>>3) ^ (row&7)
  int c1 = ((j >> 3) ^ (v & 7)) * 8 + (j & 7);
  T[v * 64 + c1] = f2bf(s1 + b1[j]);
  int r2 = 64 + v;                       // (r2 & 7) == (v & 7)
  T[r2 * 64 + c1] = f2bf(0.25f * s2);
}

// Kernel B v3: bf16 swizzled-table gather via ds_read_b128.
// Wave-group token batching + cross-group prefetch kept from v2.
__global__ __launch_bounds__(256, 4) void lru_main(
    const int* __restrict__ seqs, const int* __restrict__ qtok,
    const float* __restrict__ W2, const float* __restrict__ b2,
    const unsigned short* __restrict__ T, float* __restrict__ out, int nbatch) {
  __shared__ __align__(16) unsigned short sT[TELEMS];   // 16384 B

  const int lane = threadIdx.x & 63;
  const int quad = lane >> 4;
  const int m    = lane & 15;
  const int k0   = quad * 8;

  const int wave = blockIdx.x * (blockDim.x >> 6) + (threadIdx.x >> 6);
  const int nw   = gridDim.x * (blockDim.x >> 6);
  const int R    = nbatch * 16;             // total rows
  const int ngroup = (nbatch + 3) >> 2;     // groups of 4 batches (64 rows)

  // ---- issue first group's token loads NOW; they complete under staging ----
  int g = wave;
  int q_cur = 0, a_cur = 0;
  int4 b_cur = make_int4(0, 0, 0, 0);
  if (g < ngroup) {
    int r = g * 64 + lane; if (r >= R) r = R - 1;
    q_cur = qtok[r];                          // 256B fully coalesced per wave
    const int* sp = seqs + (size_t)r * SEQ;
    a_cur = sp[43];                           // col 43
    b_cur = *(const int4*)(sp + 44);          // cols 44,45,46,(47 unused); 16B-aligned
  }

  // cooperative stage of the table (16 KB contiguous)
  {
    const floatx4* src = (const floatx4*)T;
    floatx4* dst = (floatx4*)sT;
    for (int i = threadIdx.x; i < TELEMS / 8; i += blockDim.x) dst[i] = src[i];
  }
  __syncthreads();

  // B fragments: B[k][n] with n = lane&15 (+16*t), k = s*32 + quad*8 + j.
  frag_ab bf[4][2];
  for (int t = 0; t < 4; ++t)
    for (int s = 0; s < 2; ++s) {
      const float* w2r = W2 + (t * 16 + m) * HD + s * 32 + k0;
      for (int j = 0; j < 8; ++j) bf[t][s][j] = (short)f2bf(w2r[j]);
    }
  float b2v[4];
  for (int t = 0; t < 4; ++t) b2v[t] = b2[t * 16 + m];

  for (; g < ngroup; g += nw) {
    // ---- prefetch NEXT group's tokens (overlaps with this group's compute) ----
    const int gn = g + nw;
    int q_nxt = 0, a_nxt = 0;
    int4 b_nxt = make_int4(0, 0, 0, 0);
    if (gn < ngroup) {
      int r = gn * 64 + lane; if (r >= R) r = R - 1;
      q_nxt = qtok[r];
      const int* sp = seqs + (size_t)r * SEQ;
      a_nxt = sp[43];
      b_nxt = *(const int4*)(sp + 44);
    }

#pragma unroll
    for (int it = 0; it < 4; ++it) {
      const int b = g * 4 + it;
      if (b >= nbatch) break;                 // wave-uniform guard

      // tokens for row it*16+m live in lane it*16+m
      const int srcl = it * 16 + m;
      const int q  = __shfl(q_cur, srcl);
      const int t0 = __shfl(a_cur, srcl) + 64;
      const int t1 = __shfl(b_cur.x, srcl) + 64;
      const int t2 = __shfl(b_cur.y, srcl) + 64;
      const int t3 = __shfl(b_cur.z, srcl) + 64;

      // gather + sum 5 table rows at my 16 k-slots.
      // chunk for (row, s) sits at ushort offset row*64 + ((s*4+quad)^(row&7))*8
      float s0[8], s1[8];
      {
        const uintx4 w0 = *(const uintx4*)(sT + q * 64 + (((0 * 4 + quad) ^ (q & 7)) << 3));
        const uintx4 w1 = *(const uintx4*)(sT + q * 64 + (((1 * 4 + quad) ^ (q & 7)) << 3));
        for (int i = 0; i < 4; ++i) {
          s0[2 * i] = blo(w0[i]); s0[2 * i + 1] = bhi(w0[i]);
          s1[2 * i] = blo(w1[i]); s1[2 * i + 1] = bhi(w1[i]);
        }
        const int toks[4] = {t0, t1, t2, t3};
        for (int u = 0; u < 4; ++u) {
          const int r2 = toks[u];
          const uintx4 x0 = *(const uintx4*)(sT + r2 * 64 + (((0 * 4 + quad) ^ (r2 & 7)) << 3));
          const uintx4 x1 = *(const uintx4*)(sT + r2 * 64 + (((1 * 4 + quad) ^ (r2 & 7)) << 3));
          for (int i = 0; i < 4; ++i) {
            s0[2 * i] += blo(x0[i]); s0[2 * i + 1] += bhi(x0[i]);
            s1[2 * i] += blo(x1[i]); s1[2 * i + 1] += bhi(x1[i]);
          }
        }
      }

      // relu + bf16 pack into A fragments: A[m=lane&15][k=quad*8+j] (+32 for a1)
      frag_ab a0, a1;
      for (int i = 0; i < 8; ++i) {
        a0[i] = (short)f2bf(fmaxf(s0[i], 0.f));
        a1[i] = (short)f2bf(fmaxf(s1[i], 0.f));
      }

      frag_cd acc[4];
      for (int t = 0; t < 4; ++t) {
        acc[t] = (frag_cd){0.f, 0.f, 0.f, 0.f};
        acc[t] = __builtin_amdgcn_mfma_f32_16x16x32_bf16(a0, bf[t][0], acc[t], 0, 0, 0);
        acc[t] = __builtin_amdgcn_mfma_f32_16x16x32_bf16(a1, bf[t][1], acc[t], 0, 0, 0);
      }

      // C layout: col = lane&15, row = quad*4 + reg. Nontemporal: write-once stream.
      float* orow = out + (size_t)(b * 16) * HD;
      for (int t = 0; t < 4; ++t)
        for (int p = 0; p < 4; ++p)
          __builtin_nontemporal_store(acc[t][p] + b2v[t],
                                      &orow[(quad * 4 + p) * HD + t * 16 + m]);
    }

    q_cur = q_nxt; a_cur = a_nxt; b_cur = b_nxt;
  }
}

extern "C" void kernel_launch(void* const* d_in, const int* in_sizes, int n_in,
                              void* d_out, int out_size, void* d_ws, size_t ws_size,
                              hipStream_t stream) {
  const int*   seqs  = (const int*)d_in[0];
  const int*   qtok  = (const int*)d_in[1];
  const float* embed = (const float*)d_in[2];
  const float* W1    = (const float*)d_in[3];
  const float* b1    = (const float*)d_in[4];
  const float* W2    = (const float*)d_in[5];
  const float* b2    = (const float*)d_in[6];
  float* out = (float*)d_out;
  unsigned short* T = (unsigned short*)d_ws;   // 8192 ushort = 16384 B

  const int B = in_sizes[1];        // number of rows (524288)
  const int nbatch = B / 16;

  build_tables<<<VOCAB, HD, 0, stream>>>(embed, W1, b1, T);
  lru_main<<<1024, 256, 0, stream>>>(seqs, qtok, W2, b2, T, out, nbatch);
}

// Round 3
// 227.992 us; speedup vs baseline: 1.0492x; 1.0484x over previous
//
#include <hip/hip_runtime.h>

// Problem constants (from reference)
#define HD 64
#define VOCAB 64
#define SEQ 48

// Tables are bf16, row = 64 bf16 = 128 B = 8 chunks of 16 B.
// Chunk c of row r is stored at chunk position (c ^ (r & 7)) — XOR swizzle so a
// wave's 64 b128 reads (random rows) spread uniformly over all 8 bank groups.
// Same-row same-chunk lanes hit the same address -> LDS broadcast (free).
#define TROWS 128            // 64 T1 rows then 64 T2 rows
#define TELEMS (TROWS * 64)  // ushort count = 8192 -> 16384 B

using frag_ab = __attribute__((ext_vector_type(8))) short;   // 8 bf16
using frag_cd = __attribute__((ext_vector_type(4))) float;   // 4 fp32
typedef __attribute__((ext_vector_type(4))) float floatx4;
typedef __attribute__((ext_vector_type(4))) unsigned int uintx4;

static __device__ inline unsigned short f2bf(float f) {
  // round-to-nearest-even fp32 -> bf16
  unsigned u = __float_as_uint(f);
  unsigned r = (u + 0x7fffu + ((u >> 16) & 1u)) >> 16;
  return (unsigned short)r;
}
static __device__ inline float blo(unsigned w) { return __uint_as_float(w << 16); }
static __device__ inline float bhi(unsigned w) { return __uint_as_float(w & 0xffff0000u); }

// Kernel A: build fused first-layer tables in workspace (bf16, chunk-swizzled).
// T1[v][j] = sum_k embed[v][k]*W1[j][k] + b1[j]          (query half)
// T2[v][j] = 0.25 * sum_k embed[v][k]*W1[j][64+k]        (memory half, mean folded)
__global__ void build_tables(const float* __restrict__ embed,
                             const float* __restrict__ W1,
                             const float* __restrict__ b1,
                             unsigned short* __restrict__ T) {
  int v = blockIdx.x;    // 0..63
  int j = threadIdx.x;   // 0..63
  const float* e = embed + v * HD;
  const float* w1r = W1 + j * (2 * HD);
  float s1 = 0.f, s2 = 0.f;
  for (int k = 0; k < HD; ++k) {
    float ev = e[k];              // uniform per block -> scalar loads
    s1 += ev * w1r[k];
    s2 += ev * w1r[HD + k];
  }
  // swizzled element position within a row: chunk (j>>3) -> (j>>3) ^ (row&7)
  int c1 = ((j >> 3) ^ (v & 7)) * 8 + (j & 7);
  T[v * 64 + c1] = f2bf(s1 + b1[j]);
  int r2 = 64 + v;                       // (r2 & 7) == (v & 7)
  T[r2 * 64 + c1] = f2bf(0.25f * s2);
}

// Kernel B v4: transposed MFMA (operands swapped) so each lane owns 4
// CONSECUTIVE output floats -> global_store_dwordx4 through L2 (no nt).
// 4 store instructions/iter instead of 16 scattered dword nt-stores.
__global__ __launch_bounds__(256, 4) void lru_main(
    const int* __restrict__ seqs, const int* __restrict__ qtok,
    const float* __restrict__ W2, const float* __restrict__ b2,
    const unsigned short* __restrict__ T, float* __restrict__ out, int nbatch) {
  __shared__ __align__(16) unsigned short sT[TELEMS];   // 16384 B

  const int lane = threadIdx.x & 63;
  const int quad = lane >> 4;
  const int m    = lane & 15;
  const int k0   = quad * 8;

  const int wave = blockIdx.x * (blockDim.x >> 6) + (threadIdx.x >> 6);
  const int nw   = gridDim.x * (blockDim.x >> 6);
  const int R    = nbatch * 16;             // total rows
  const int ngroup = (nbatch + 3) >> 2;     // groups of 4 batches (64 rows)

  // ---- issue first group's token loads NOW; they complete under staging ----
  int g = wave;
  int q_cur = 0, a_cur = 0;
  int4 b_cur = make_int4(0, 0, 0, 0);
  if (g < ngroup) {
    int r = g * 64 + lane; if (r >= R) r = R - 1;
    q_cur = qtok[r];                          // 256B fully coalesced per wave
    const int* sp = seqs + (size_t)r * SEQ;
    a_cur = sp[43];                           // col 43
    b_cur = *(const int4*)(sp + 44);          // cols 44,45,46,(47 unused); 16B-aligned
  }

  // cooperative stage of the table (16 KB contiguous)
  {
    const floatx4* src = (const floatx4*)T;
    floatx4* dst = (floatx4*)sT;
    for (int i = threadIdx.x; i < TELEMS / 8; i += blockDim.x) dst[i] = src[i];
  }
  __syncthreads();

  // W2 fragments (now the A-operand of the transposed MFMA):
  // A[am=lane&15][k = s*32 + quad*8 + j] = W2[t*16+am][k]
  frag_ab bf[4][2];
  for (int t = 0; t < 4; ++t)
    for (int s = 0; s < 2; ++s) {
      const float* w2r = W2 + (t * 16 + m) * HD + s * 32 + k0;
      for (int j = 0; j < 8; ++j) bf[t][s][j] = (short)f2bf(w2r[j]);
    }
  // bias pre-loaded into C-init: lane (quad,m) owns out cols t*16+quad*4 .. +3
  frag_cd bini[4];
  for (int t = 0; t < 4; ++t)
    bini[t] = *(const floatx4*)(b2 + t * 16 + quad * 4);

  for (; g < ngroup; g += nw) {
    // ---- prefetch NEXT group's tokens (overlaps with this group's compute) ----
    const int gn = g + nw;
    int q_nxt = 0, a_nxt = 0;
    int4 b_nxt = make_int4(0, 0, 0, 0);
    if (gn < ngroup) {
      int r = gn * 64 + lane; if (r >= R) r = R - 1;
      q_nxt = qtok[r];
      const int* sp = seqs + (size_t)r * SEQ;
      a_nxt = sp[43];
      b_nxt = *(const int4*)(sp + 44);
    }

#pragma unroll
    for (int it = 0; it < 4; ++it) {
      const int b = g * 4 + it;
      if (b >= nbatch) break;                 // wave-uniform guard

      // tokens for row it*16+m live in lane it*16+m
      const int srcl = it * 16 + m;
      const int q  = __shfl(q_cur, srcl);
      const int t0 = __shfl(a_cur, srcl) + 64;
      const int t1 = __shfl(b_cur.x, srcl) + 64;
      const int t2 = __shfl(b_cur.y, srcl) + 64;
      const int t3 = __shfl(b_cur.z, srcl) + 64;

      // gather + sum 5 table rows at my 16 k-slots.
      // chunk for (row, s) sits at ushort offset row*64 + ((s*4+quad)^(row&7))*8
      float s0[8], s1[8];
      {
        const uintx4 w0 = *(const uintx4*)(sT + q * 64 + (((0 * 4 + quad) ^ (q & 7)) << 3));
        const uintx4 w1 = *(const uintx4*)(sT + q * 64 + (((1 * 4 + quad) ^ (q & 7)) << 3));
        for (int i = 0; i < 4; ++i) {
          s0[2 * i] = blo(w0[i]); s0[2 * i + 1] = bhi(w0[i]);
          s1[2 * i] = blo(w1[i]); s1[2 * i + 1] = bhi(w1[i]);
        }
        const int toks[4] = {t0, t1, t2, t3};
        for (int u = 0; u < 4; ++u) {
          const int r2 = toks[u];
          const uintx4 x0 = *(const uintx4*)(sT + r2 * 64 + (((0 * 4 + quad) ^ (r2 & 7)) << 3));
          const uintx4 x1 = *(const uintx4*)(sT + r2 * 64 + (((1 * 4 + quad) ^ (r2 & 7)) << 3));
          for (int i = 0; i < 4; ++i) {
            s0[2 * i] += blo(x0[i]); s0[2 * i + 1] += bhi(x0[i]);
            s1[2 * i] += blo(x1[i]); s1[2 * i + 1] += bhi(x1[i]);
          }
        }
      }

      // relu + bf16 pack: B-operand fragment B[k][bn=lane&15] = h[bn][k]
      frag_ab a0, a1;
      for (int i = 0; i < 8; ++i) {
        a0[i] = (short)f2bf(fmaxf(s0[i], 0.f));
        a1[i] = (short)f2bf(fmaxf(s1[i], 0.f));
      }

      // Transposed product: D[am][bn] = sum_k W2[t*16+am][k] * h[bn][k]
      // Lane (quad,m): D rows am=quad*4+p (out cols), col bn=m (batch row).
      frag_cd acc[4];
      for (int t = 0; t < 4; ++t) {
        acc[t] = bini[t];
        acc[t] = __builtin_amdgcn_mfma_f32_16x16x32_bf16(bf[t][0], a0, acc[t], 0, 0, 0);
        acc[t] = __builtin_amdgcn_mfma_f32_16x16x32_bf16(bf[t][1], a1, acc[t], 0, 0, 0);
      }

      // Store: lane (quad,m) writes out[rb+m][t*16+quad*4 .. +3] as dwordx4.
      float* orow = out + ((size_t)(b * 16) + m) * HD + quad * 4;
      for (int t = 0; t < 4; ++t)
        *(floatx4*)(orow + t * 16) = acc[t];
    }

    q_cur = q_nxt; a_cur = a_nxt; b_cur = b_nxt;
  }
}

extern "C" void kernel_launch(void* const* d_in, const int* in_sizes, int n_in,
                              void* d_out, int out_size, void* d_ws, size_t ws_size,
                              hipStream_t stream) {
  const int*   seqs  = (const int*)d_in[0];
  const int*   qtok  = (const int*)d_in[1];
  const float* embed = (const float*)d_in[2];
  const float* W1    = (const float*)d_in[3];
  const float* b1    = (const float*)d_in[4];
  const float* W2    = (const float*)d_in[5];
  const float* b2    = (const float*)d_in[6];
  float* out = (float*)d_out;
  unsigned short* T = (unsigned short*)d_ws;   // 8192 ushort = 16384 B

  const int B = in_sizes[1];        // number of rows (524288)
  const int nbatch = B / 16;

  build_tables<<<VOCAB, HD, 0, stream>>>(embed, W1, b1, T);
  lru_main<<<1024, 256, 0, stream>>>(seqs, qtok, W2, b2, T, out, nbatch);
}